// Round 1
// baseline (372.493 us; speedup 1.0000x reference)
//
#include <hip/hip_runtime.h>
#include <math.h>

#define NP   8192
#define CD   512
#define KD   64
#define TWON 16384

// ---------------------------------------------------------------------------
// K0: prep. VT[cc][k] for cc in [0,1024): cc<512 pairs with f (2*m*inv2),
// cc>=512 pairs with f^2 (-inv2). cst[k] = sum_c m^2*inv2.
// dist[n,k] = sum_cc U[n,cc]*VT[cc,k] - cst[k],  U = [f | f^2]
// ---------------------------------------------------------------------------
__global__ __launch_bounds__(256) void prep_kernel(
    const float* __restrict__ means, const float* __restrict__ scales,
    float* __restrict__ VT, float* __restrict__ cst)
{
    const int k = blockIdx.x;   // 64 blocks, one per k
    const int t = threadIdx.x;  // 256 threads
    __shared__ float red[256];
    float local = 0.f;
    for (int c = t; c < CD; c += 256) {
        float m    = means[k * CD + c];
        float s    = scales[k * CD + c];
        float inv  = 1.0f / s;
        float inv2 = inv * inv;
        VT[c * KD + k]        = 2.0f * m * inv2;  // pairs with f
        VT[(CD + c) * KD + k] = -inv2;            // pairs with f^2
        local += m * m * inv2;
    }
    red[t] = local;
    __syncthreads();
    for (int off = 128; off > 0; off >>= 1) {
        if (t < off) red[t] += red[t + off];
        __syncthreads();
    }
    if (t == 0) cst[k] = red[0];
}

// ---------------------------------------------------------------------------
// K1: phiT[64][16384]. Block = 32 rows x all 64 k; 256 threads;
// micro-tile 2 rows x 4 k per thread. Contraction over cc in chunks of 64.
// Rows [0,8192) come from f_i (weights applied), [8192,16384) from f_j.
// ---------------------------------------------------------------------------
__global__ __launch_bounds__(256) void phi_kernel(
    const float* __restrict__ f_i, const float* __restrict__ f_j,
    const float* __restrict__ VT, const float* __restrict__ cst,
    const float* __restrict__ weights, float* __restrict__ phiT)
{
    __shared__ float Us[64 * 33];  // [cc][row], pad 33 -> 2-way max on store
    __shared__ float Vs[64 * 68];  // [cc][k],  pad 68 keeps float4 align
    const int t  = threadIdx.x;
    const int n0 = blockIdx.x * 32;
    const bool iside = (n0 < NP);
    const float* f = iside ? (f_i + (size_t)n0 * CD)
                           : (f_j + (size_t)(n0 - NP) * CD);

    const int k0 = (t & 15) * 4;
    const int r0 = (t >> 4) * 2;
    float acc[2][4] = {};

    for (int ch = 0; ch < 16; ++ch) {
        const int gc = ch * 64;            // virtual cc base
        const bool sq = (ch >= 8);
        const int fc = sq ? (gc - CD) : gc;  // f column base

        // stage U chunk: 32 rows x 64 cc  (512 float4 loads)
        #pragma unroll
        for (int j = 0; j < 2; ++j) {
            int v   = t + j * 256;         // 0..511
            int row = v >> 4;
            int c4  = (v & 15) * 4;
            float4 val = *(const float4*)(f + (size_t)row * CD + fc + c4);
            if (sq) { val.x *= val.x; val.y *= val.y; val.z *= val.z; val.w *= val.w; }
            Us[(c4 + 0) * 33 + row] = val.x;
            Us[(c4 + 1) * 33 + row] = val.y;
            Us[(c4 + 2) * 33 + row] = val.z;
            Us[(c4 + 3) * 33 + row] = val.w;
        }
        // stage V chunk: 64 cc x 64 k (1024 float4 loads, coalesced in k)
        #pragma unroll
        for (int j = 0; j < 4; ++j) {
            int v  = t + j * 256;          // 0..1023
            int cc = v >> 4;
            int k4 = (v & 15) * 4;
            float4 val = *(const float4*)(VT + (size_t)(gc + cc) * KD + k4);
            *(float4*)&Vs[cc * 68 + k4] = val;
        }
        __syncthreads();

        #pragma unroll 8
        for (int cc = 0; cc < 64; ++cc) {
            float a0 = Us[cc * 33 + r0];
            float a1 = Us[cc * 33 + r0 + 1];
            float4 b = *(const float4*)&Vs[cc * 68 + k0];
            acc[0][0] += a0 * b.x; acc[0][1] += a0 * b.y;
            acc[0][2] += a0 * b.z; acc[0][3] += a0 * b.w;
            acc[1][0] += a1 * b.x; acc[1][1] += a1 * b.y;
            acc[1][2] += a1 * b.z; acc[1][3] += a1 * b.w;
        }
        __syncthreads();
    }

    const float4 cst4 = *(const float4*)&cst[k0];
    float4 wv4 = make_float4(1.f, 1.f, 1.f, 1.f);
    if (iside) wv4 = *(const float4*)&weights[k0];
    const float cs[4] = {cst4.x, cst4.y, cst4.z, cst4.w};
    const float wv[4] = {wv4.x, wv4.y, wv4.z, wv4.w};
    #pragma unroll
    for (int r = 0; r < 2; ++r) {
        #pragma unroll
        for (int kj = 0; kj < 4; ++kj) {
            float ph = expf(acc[r][kj] - cs[kj]) * wv[kj];
            phiT[(size_t)(k0 + kj) * TWON + n0 + r0 + r] = ph;
        }
    }
}

// ---------------------------------------------------------------------------
// K2: out[8192][8192] = phi_i @ phi_j^T. Block tile 128x128, 256 threads,
// 8x8 micro-tile, full K=64 staged once (no k-loop over tiles). 64 KB LDS.
// ---------------------------------------------------------------------------
__global__ __launch_bounds__(256) void gemm_kernel(
    const float* __restrict__ phiT, float* __restrict__ out)
{
    __shared__ float As[64 * 128];  // [k][i-row]
    __shared__ float Bs[64 * 128];  // [k][j-row]
    const int t  = threadIdx.x;
    const int rb = blockIdx.y * 128;  // i rows
    const int cb = blockIdx.x * 128;  // j rows

    #pragma unroll
    for (int j = 0; j < 8; ++j) {
        int v = t + j * 256;          // 0..2047 (float4 index)
        int k = v >> 5;
        int r = (v & 31) * 4;
        *(float4*)&As[k * 128 + r] =
            *(const float4*)&phiT[(size_t)k * TWON + rb + r];
        *(float4*)&Bs[k * 128 + r] =
            *(const float4*)&phiT[(size_t)k * TWON + NP + cb + r];
    }
    __syncthreads();

    const int c0 = (t & 15) * 8;   // j-col within tile (adjacent lanes ->
    const int r0 = (t >> 4) * 8;   //   adjacent cols -> coalesced stores)
    float acc[8][8] = {};

    #pragma unroll 8
    for (int k = 0; k < 64; ++k) {
        float4 a0 = *(const float4*)&As[k * 128 + r0];
        float4 a1 = *(const float4*)&As[k * 128 + r0 + 4];
        float4 b0 = *(const float4*)&Bs[k * 128 + c0];
        float4 b1 = *(const float4*)&Bs[k * 128 + c0 + 4];
        float a[8] = {a0.x, a0.y, a0.z, a0.w, a1.x, a1.y, a1.z, a1.w};
        float b[8] = {b0.x, b0.y, b0.z, b0.w, b1.x, b1.y, b1.z, b1.w};
        #pragma unroll
        for (int ri = 0; ri < 8; ++ri)
            #pragma unroll
            for (int cj = 0; cj < 8; ++cj)
                acc[ri][cj] += a[ri] * b[cj];
    }

    #pragma unroll
    for (int ri = 0; ri < 8; ++ri) {
        size_t row = (size_t)(rb + r0 + ri);
        float4* o = (float4*)&out[row * NP + cb + c0];
        o[0] = make_float4(acc[ri][0], acc[ri][1], acc[ri][2], acc[ri][3]);
        o[1] = make_float4(acc[ri][4], acc[ri][5], acc[ri][6], acc[ri][7]);
    }
}

// ---------------------------------------------------------------------------
extern "C" void kernel_launch(void* const* d_in, const int* in_sizes, int n_in,
                              void* d_out, int out_size, void* d_ws, size_t ws_size,
                              hipStream_t stream) {
    const float* f_i     = (const float*)d_in[0];
    const float* f_j     = (const float*)d_in[1];
    const float* means   = (const float*)d_in[2];
    const float* scales  = (const float*)d_in[3];
    const float* weights = (const float*)d_in[4];
    float* out = (float*)d_out;

    float* ws   = (float*)d_ws;
    float* VT   = ws;            // 1024*64 = 65536 floats
    float* cst  = ws + 65536;    // 64 floats
    float* phiT = ws + 65600;    // 64*16384 = 1048576 floats (~4.25 MB total)

    prep_kernel<<<64, 256, 0, stream>>>(means, scales, VT, cst);
    phi_kernel<<<512, 256, 0, stream>>>(f_i, f_j, VT, cst, weights, phiT);
    gemm_kernel<<<dim3(64, 64), 256, 0, stream>>>(phiT, out);
}

// Round 2
// 357.349 us; speedup vs baseline: 1.0424x; 1.0424x over previous
//
#include <hip/hip_runtime.h>
#include <hip/hip_bf16.h>
#include <math.h>

#define NP   8192
#define CD   512
#define KD   64
#define TWON 16384

typedef __attribute__((ext_vector_type(8))) short short8;
typedef __attribute__((ext_vector_type(4))) float f32x4;

// ---------------------------------------------------------------------------
// K0: prep. VT[cc][k] for cc in [0,1024): cc<512 -> 2*m*inv2 (pairs with f),
// cc>=512 -> -inv2 (pairs with f^2). cst[k] = sum_c m^2*inv2.
// dist[n,k] = sum_cc U[n,cc]*VT[cc,k] - cst[k],  U = [f | f^2]
// ---------------------------------------------------------------------------
__global__ __launch_bounds__(256) void prep_kernel(
    const float* __restrict__ means, const float* __restrict__ scales,
    float* __restrict__ VT, float* __restrict__ cst)
{
    const int k = blockIdx.x;
    const int t = threadIdx.x;
    __shared__ float red[256];
    float local = 0.f;
    for (int c = t; c < CD; c += 256) {
        float m    = means[k * CD + c];
        float s    = scales[k * CD + c];
        float inv  = 1.0f / s;
        float inv2 = inv * inv;
        VT[c * KD + k]        = 2.0f * m * inv2;
        VT[(CD + c) * KD + k] = -inv2;
        local += m * m * inv2;
    }
    red[t] = local;
    __syncthreads();
    for (int off = 128; off > 0; off >>= 1) {
        if (t < off) red[t] += red[t + off];
        __syncthreads();
    }
    if (t == 0) cst[k] = red[0];
}

// ---------------------------------------------------------------------------
// K1: phi bf16 [16384][64] row-major. 256 blocks x 64 rows. Thread = 2 rows
// (rg, rg+32) x 8 k. One pass over c: a and a^2 both contracted (Vs1/Vs2).
// Rows [0,8192) from f_i (weights applied), rest from f_j.
// ---------------------------------------------------------------------------
__global__ __launch_bounds__(256) void phi_kernel(
    const float* __restrict__ f_i, const float* __restrict__ f_j,
    const float* __restrict__ VT, const float* __restrict__ cst,
    const float* __restrict__ weights, __hip_bfloat16* __restrict__ phi)
{
    __shared__ float Us [64 * 68];  // [row][c]  pad 68: b128-aligned, 2-way max
    __shared__ float Vs1[64 * 68];  // [c][k]
    __shared__ float Vs2[64 * 68];  // [c][k]
    const int t  = threadIdx.x;
    const int n0 = blockIdx.x * 64;
    const bool iside = (n0 < NP);
    const float* f = iside ? (f_i + (size_t)n0 * CD)
                           : (f_j + (size_t)(n0 - NP) * CD);

    const int k0 = (t & 7) * 8;   // 8 k per thread
    const int rg = t >> 3;        // 0..31; rows rg and rg+32
    float acc[2][8] = {};

    for (int ch = 0; ch < 8; ++ch) {
        const int c0 = ch * 64;
        #pragma unroll
        for (int j = 0; j < 4; ++j) {
            int v   = t + j * 256;        // 0..1023
            int row = v >> 4;             // 0..63
            int c4  = (v & 15) * 4;       // 0..60
            *(float4*)&Us[row * 68 + c4] =
                *(const float4*)&f[(size_t)row * CD + c0 + c4];
            *(float4*)&Vs1[row * 68 + c4] =
                *(const float4*)&VT[(size_t)(c0 + row) * KD + c4];
            *(float4*)&Vs2[row * 68 + c4] =
                *(const float4*)&VT[(size_t)(CD + c0 + row) * KD + c4];
        }
        __syncthreads();

        #pragma unroll 8
        for (int cc = 0; cc < 64; ++cc) {
            float a0 = Us[rg * 68 + cc];
            float a1 = Us[(rg + 32) * 68 + cc];
            float s0 = a0 * a0, s1 = a1 * a1;
            float4 b1a = *(const float4*)&Vs1[cc * 68 + k0];
            float4 b1b = *(const float4*)&Vs1[cc * 68 + k0 + 4];
            float4 b2a = *(const float4*)&Vs2[cc * 68 + k0];
            float4 b2b = *(const float4*)&Vs2[cc * 68 + k0 + 4];
            acc[0][0] += a0 * b1a.x + s0 * b2a.x;
            acc[0][1] += a0 * b1a.y + s0 * b2a.y;
            acc[0][2] += a0 * b1a.z + s0 * b2a.z;
            acc[0][3] += a0 * b1a.w + s0 * b2a.w;
            acc[0][4] += a0 * b1b.x + s0 * b2b.x;
            acc[0][5] += a0 * b1b.y + s0 * b2b.y;
            acc[0][6] += a0 * b1b.z + s0 * b2b.z;
            acc[0][7] += a0 * b1b.w + s0 * b2b.w;
            acc[1][0] += a1 * b1a.x + s1 * b2a.x;
            acc[1][1] += a1 * b1a.y + s1 * b2a.y;
            acc[1][2] += a1 * b1a.z + s1 * b2a.z;
            acc[1][3] += a1 * b1a.w + s1 * b2a.w;
            acc[1][4] += a1 * b1b.x + s1 * b2b.x;
            acc[1][5] += a1 * b1b.y + s1 * b2b.y;
            acc[1][6] += a1 * b1b.z + s1 * b2b.z;
            acc[1][7] += a1 * b1b.w + s1 * b2b.w;
        }
        __syncthreads();
    }

    float cs[8], wv[8];
    *(float4*)&cs[0] = *(const float4*)&cst[k0];
    *(float4*)&cs[4] = *(const float4*)&cst[k0 + 4];
    if (iside) {
        *(float4*)&wv[0] = *(const float4*)&weights[k0];
        *(float4*)&wv[4] = *(const float4*)&weights[k0 + 4];
    } else {
        #pragma unroll
        for (int j = 0; j < 8; ++j) wv[j] = 1.0f;
    }
    #pragma unroll
    for (int r = 0; r < 2; ++r) {
        int row = n0 + rg + r * 32;
        union { short8 v; __hip_bfloat16 h[8]; } o;
        #pragma unroll
        for (int j = 0; j < 8; ++j) {
            float ph = expf(acc[r][j] - cs[j]) * wv[j];
            o.h[j] = __float2bfloat16(ph);
        }
        *(short8*)&phi[(size_t)row * KD + k0] = o.v;
    }
}

// ---------------------------------------------------------------------------
// K2: out = phi_i @ phi_j^T via mfma_f32_16x16x32_bf16, zero LDS.
// phi is [16384][64] bf16 row-major; A-frag = contiguous 16B row slice:
// A[m=lane&15][k=quad*8+j]; B-frag identical with n=lane&15 (B^T layout).
// C/D: col=lane&15, row=quad*4+reg. Block 128x128 (4 waves x 64x64 quadrant).
// ---------------------------------------------------------------------------
__global__ __launch_bounds__(256) void gemm_kernel(
    const __hip_bfloat16* __restrict__ phi, float* __restrict__ out)
{
    const int t    = threadIdx.x;
    const int lane = t & 63, wave = t >> 6;
    const int m    = lane & 15, q = lane >> 4;
    const int i0   = blockIdx.y * 128 + (wave & 1) * 64;
    const int j0   = blockIdx.x * 128 + (wave >> 1) * 64;
    const short* phiS = (const short*)phi;

    short8 A[4][2], B[4][2];
    #pragma unroll
    for (int it = 0; it < 4; ++it)
        #pragma unroll
        for (int kh = 0; kh < 2; ++kh) {
            A[it][kh] = *(const short8*)
                &phiS[(size_t)(i0 + it * 16 + m) * KD + kh * 32 + q * 8];
            B[it][kh] = *(const short8*)
                &phiS[(size_t)(NP + j0 + it * 16 + m) * KD + kh * 32 + q * 8];
        }

    f32x4 acc[4][4];
    #pragma unroll
    for (int it = 0; it < 4; ++it)
        #pragma unroll
        for (int jt = 0; jt < 4; ++jt)
            acc[it][jt] = (f32x4){0.f, 0.f, 0.f, 0.f};

    #pragma unroll
    for (int it = 0; it < 4; ++it)
        #pragma unroll
        for (int jt = 0; jt < 4; ++jt) {
            acc[it][jt] = __builtin_amdgcn_mfma_f32_16x16x32_bf16(
                A[it][0], B[jt][0], acc[it][jt], 0, 0, 0);
            acc[it][jt] = __builtin_amdgcn_mfma_f32_16x16x32_bf16(
                A[it][1], B[jt][1], acc[it][jt], 0, 0, 0);
        }

    #pragma unroll
    for (int it = 0; it < 4; ++it)
        #pragma unroll
        for (int r = 0; r < 4; ++r) {
            size_t row = (size_t)(i0 + it * 16 + q * 4 + r);
            #pragma unroll
            for (int jt = 0; jt < 4; ++jt)
                out[row * NP + j0 + jt * 16 + m] = acc[it][jt][r];
        }
}

// ---------------------------------------------------------------------------
extern "C" void kernel_launch(void* const* d_in, const int* in_sizes, int n_in,
                              void* d_out, int out_size, void* d_ws, size_t ws_size,
                              hipStream_t stream) {
    const float* f_i     = (const float*)d_in[0];
    const float* f_j     = (const float*)d_in[1];
    const float* means   = (const float*)d_in[2];
    const float* scales  = (const float*)d_in[3];
    const float* weights = (const float*)d_in[4];
    float* out = (float*)d_out;

    float* ws   = (float*)d_ws;
    float* VT   = ws;            // 1024*64 = 65536 floats
    float* cst  = ws + 65536;    // 64 floats
    __hip_bfloat16* phi = (__hip_bfloat16*)(ws + 65600);  // 16384*64 bf16 = 2 MB

    prep_kernel<<<64, 256, 0, stream>>>(means, scales, VT, cst);
    phi_kernel<<<256, 256, 0, stream>>>(f_i, f_j, VT, cst, weights, phi);
    gemm_kernel<<<dim3(64, 64), 256, 0, stream>>>(phi, out);
}

// Round 3
// 335.995 us; speedup vs baseline: 1.1086x; 1.0636x over previous
//
#include <hip/hip_runtime.h>
#include <hip/hip_bf16.h>
#include <math.h>

#define NP   8192
#define CD   512
#define KD   64
#define TWON 16384
#define CC   1024   // virtual contraction: [f | f^2]

typedef __attribute__((ext_vector_type(8))) short short8;
typedef __attribute__((ext_vector_type(4))) float f32x4;

__device__ __forceinline__ void split_bf16(float x, __hip_bfloat16& h, __hip_bfloat16& l) {
    h = __float2bfloat16(x);
    l = __float2bfloat16(x - __bfloat162float(h));
}

// ---------------------------------------------------------------------------
// K0: prep. VTT[k][cc] (bf16 hi/lo), cc<512 -> 2*m*inv2 (pairs with f),
// cc>=512 -> -inv2 (pairs with f^2). cst[k] = sum_c m^2*inv2 (fp32).
// dist[n,k] = sum_cc U[n,cc]*VTT[k,cc] - cst[k],  U = [f | f^2]
// ---------------------------------------------------------------------------
__global__ __launch_bounds__(256) void prep_kernel(
    const float* __restrict__ means, const float* __restrict__ scales,
    __hip_bfloat16* __restrict__ VTT_hi, __hip_bfloat16* __restrict__ VTT_lo,
    float* __restrict__ cst)
{
    const int k = blockIdx.x;
    const int t = threadIdx.x;
    __shared__ float red[256];
    float local = 0.f;
    for (int c = t; c < CD; c += 256) {
        float m    = means[k * CD + c];
        float s    = scales[k * CD + c];
        float inv  = 1.0f / s;
        float inv2 = inv * inv;
        __hip_bfloat16 h, l;
        split_bf16(2.0f * m * inv2, h, l);
        VTT_hi[(size_t)k * CC + c] = h;
        VTT_lo[(size_t)k * CC + c] = l;
        split_bf16(-inv2, h, l);
        VTT_hi[(size_t)k * CC + CD + c] = h;
        VTT_lo[(size_t)k * CC + CD + c] = l;
        local += m * m * inv2;
    }
    red[t] = local;
    __syncthreads();
    for (int off = 128; off > 0; off >>= 1) {
        if (t < off) red[t] += red[t + off];
        __syncthreads();
    }
    if (t == 0) cst[k] = red[0];
}

// ---------------------------------------------------------------------------
// K1: phi bf16 [16384][64] via MFMA, zero LDS. 256 blocks x 64 rows
// (wave = 16-row m-tile, all 64 k-outs = 4 n-tiles). A = f rows split to
// bf16 hi/lo in-register (linear + squared), B = VTT hi/lo (L2-resident).
// Compensated product: AhBh + AhBl + AlBh  (drops ~2^-18 AlBl term).
// ---------------------------------------------------------------------------
__global__ __launch_bounds__(256) void phi_kernel(
    const float* __restrict__ f_i, const float* __restrict__ f_j,
    const __hip_bfloat16* __restrict__ VTT_hi,
    const __hip_bfloat16* __restrict__ VTT_lo,
    const float* __restrict__ cst, const float* __restrict__ weights,
    __hip_bfloat16* __restrict__ phi)
{
    const int t = threadIdx.x, lane = t & 63, wave = t >> 6;
    const int q = lane >> 4, m = lane & 15;
    const int base = blockIdx.x * 64 + wave * 16;   // wave's 16-row m-tile
    const bool iside = (base < NP);                 // uniform per block
    const float* frow = iside ? &f_i[(size_t)(base + m) * CD]
                              : &f_j[(size_t)(base + m - NP) * CD];
    const short* BH = (const short*)VTT_hi;
    const short* BL = (const short*)VTT_lo;

    f32x4 acc[4];
    #pragma unroll
    for (int nt = 0; nt < 4; ++nt) acc[nt] = (f32x4){0.f, 0.f, 0.f, 0.f};

    for (int ch = 0; ch < 16; ++ch) {
        const int c0 = ch * 32 + q * 8;
        float4 x0 = *(const float4*)&frow[c0];
        float4 x1 = *(const float4*)&frow[c0 + 4];
        float xs[8] = {x0.x, x0.y, x0.z, x0.w, x1.x, x1.y, x1.z, x1.w};
        union { short8 v; __hip_bfloat16 h[8]; } aLh, aLl, aSh, aSl;
        #pragma unroll
        for (int j = 0; j < 8; ++j) {
            __hip_bfloat16 h, l;
            split_bf16(xs[j], h, l);          aLh.h[j] = h; aLl.h[j] = l;
            split_bf16(xs[j] * xs[j], h, l);  aSh.h[j] = h; aSl.h[j] = l;
        }
        #pragma unroll
        for (int nt = 0; nt < 4; ++nt) {
            const size_t boff = (size_t)(nt * 16 + m) * CC + c0;
            short8 bh0 = *(const short8*)&BH[boff];
            short8 bl0 = *(const short8*)&BL[boff];
            short8 bh1 = *(const short8*)&BH[boff + CD];
            short8 bl1 = *(const short8*)&BL[boff + CD];
            acc[nt] = __builtin_amdgcn_mfma_f32_16x16x32_bf16(aLh.v, bh0, acc[nt], 0, 0, 0);
            acc[nt] = __builtin_amdgcn_mfma_f32_16x16x32_bf16(aLh.v, bl0, acc[nt], 0, 0, 0);
            acc[nt] = __builtin_amdgcn_mfma_f32_16x16x32_bf16(aLl.v, bh0, acc[nt], 0, 0, 0);
            acc[nt] = __builtin_amdgcn_mfma_f32_16x16x32_bf16(aSh.v, bh1, acc[nt], 0, 0, 0);
            acc[nt] = __builtin_amdgcn_mfma_f32_16x16x32_bf16(aSh.v, bl1, acc[nt], 0, 0, 0);
            acc[nt] = __builtin_amdgcn_mfma_f32_16x16x32_bf16(aSl.v, bh1, acc[nt], 0, 0, 0);
        }
    }

    // D layout: row (=data row within m-tile) = q*4+r, col (=k-out) = lane&15
    #pragma unroll
    for (int nt = 0; nt < 4; ++nt) {
        const int kout = nt * 16 + m;
        const float cs = cst[kout];
        const float wv = iside ? weights[kout] : 1.0f;
        #pragma unroll
        for (int r = 0; r < 4; ++r) {
            const int row = base + q * 4 + r;
            float ph = expf(acc[nt][r] - cs) * wv;
            phi[(size_t)row * KD + kout] = __float2bfloat16(ph);
        }
    }
}

// ---------------------------------------------------------------------------
// K2: out = phi_i @ phi_j^T via mfma_f32_16x16x32_bf16, zero LDS.
// A-operand = phi_j rows (m-dim = j), B-operand = phi_i rows (n-dim = i)
// so each lane's 4 acc regs are 4 CONSECUTIVE j of one i-row -> dwordx4 store.
// Block 128x128 (4 waves x 64x64 quadrant).
// ---------------------------------------------------------------------------
__global__ __launch_bounds__(256) void gemm_kernel(
    const __hip_bfloat16* __restrict__ phi, float* __restrict__ out)
{
    const int t = threadIdx.x, lane = t & 63, wave = t >> 6;
    const int q = lane >> 4, m = lane & 15;
    const int i0 = blockIdx.y * 128 + (wave & 1) * 64;
    const int j0 = blockIdx.x * 128 + (wave >> 1) * 64;
    const short* phiS = (const short*)phi;

    short8 Aj[4][2], Bi[4][2];
    #pragma unroll
    for (int tt = 0; tt < 4; ++tt)
        #pragma unroll
        for (int kh = 0; kh < 2; ++kh) {
            Aj[tt][kh] = *(const short8*)
                &phiS[(size_t)(NP + j0 + tt * 16 + m) * KD + kh * 32 + q * 8];
            Bi[tt][kh] = *(const short8*)
                &phiS[(size_t)(i0 + tt * 16 + m) * KD + kh * 32 + q * 8];
        }

    f32x4 acc[4][4];   // [i-tile][j-tile]
    #pragma unroll
    for (int bt = 0; bt < 4; ++bt)
        #pragma unroll
        for (int at = 0; at < 4; ++at)
            acc[bt][at] = (f32x4){0.f, 0.f, 0.f, 0.f};

    #pragma unroll
    for (int bt = 0; bt < 4; ++bt)
        #pragma unroll
        for (int at = 0; at < 4; ++at) {
            acc[bt][at] = __builtin_amdgcn_mfma_f32_16x16x32_bf16(
                Aj[at][0], Bi[bt][0], acc[bt][at], 0, 0, 0);
            acc[bt][at] = __builtin_amdgcn_mfma_f32_16x16x32_bf16(
                Aj[at][1], Bi[bt][1], acc[bt][at], 0, 0, 0);
        }

    // D: row(q*4+r) = j within at-tile, col(lane&15) = i within bt-tile
    #pragma unroll
    for (int bt = 0; bt < 4; ++bt) {
        const size_t row = (size_t)(i0 + bt * 16 + m);
        #pragma unroll
        for (int at = 0; at < 4; ++at)
            *(float4*)&out[row * NP + j0 + at * 16 + q * 4] =
                (float4){acc[bt][at][0], acc[bt][at][1],
                         acc[bt][at][2], acc[bt][at][3]};
    }
}

// ---------------------------------------------------------------------------
extern "C" void kernel_launch(void* const* d_in, const int* in_sizes, int n_in,
                              void* d_out, int out_size, void* d_ws, size_t ws_size,
                              hipStream_t stream) {
    const float* f_i     = (const float*)d_in[0];
    const float* f_j     = (const float*)d_in[1];
    const float* means   = (const float*)d_in[2];
    const float* scales  = (const float*)d_in[3];
    const float* weights = (const float*)d_in[4];
    float* out = (float*)d_out;

    char* ws = (char*)d_ws;
    __hip_bfloat16* VTT_hi = (__hip_bfloat16*)(ws);            // 64*1024*2 = 128 KB
    __hip_bfloat16* VTT_lo = (__hip_bfloat16*)(ws + 131072);   // 128 KB
    float*          cst    = (float*)(ws + 262144);            // 256 B
    __hip_bfloat16* phi    = (__hip_bfloat16*)(ws + 262400);   // 16384*64*2 = 2 MB

    prep_kernel<<<64, 256, 0, stream>>>(means, scales, VTT_hi, VTT_lo, cst);
    phi_kernel<<<256, 256, 0, stream>>>(f_i, f_j, VTT_hi, VTT_lo, cst, weights, phi);
    gemm_kernel<<<dim3(64, 64), 256, 0, stream>>>(phi, out);
}